// Round 1
// baseline (13264.400 us; speedup 1.0000x reference)
//
#include <hip/hip_runtime.h>
#include <math.h>

// Problem constants
#define BB 8
#define CC 256
#define HH 128
#define WW 128
#define KK 4
#define HW (HH*WW)              // 16384
#define PLANE_ELEMS ((size_t)BB*CC*HH*WW)   // 33554432
#define CP_OFF 33554432

// ws layout (float offsets)
#define WS_SUM1 0            // [8][256]
#define WS_MAX1 2048         // [8][256]
#define WS_P2S  4096         // [8][64][128]
#define WS_P2M  69632        // [8][64][128]
#define WS_SUM3 135168       // [8][128]
#define WS_MAX3 136192       // [8][128]
#define WS_U2   137216       // [8][128][4]
#define WS_U3   141312       // [8][128][4]
#define WS_V1   145408       // [8][256][4]
#define WS_SPEC 153600       // [8][256]

// ---------------------------------------------------------------------------
// K1: direct 3x3 conv (SAME), x = concat(frm, other) on channel axis,
//     + bias + LeakyReLU(0.01). Output Fm in [B,C,H,W] fp32.
// block(128,4): tid.x = w, tid.y = c-sub. grid(H/4, C/4, B). 4 h-rows/thread.
// ---------------------------------------------------------------------------
__global__ __launch_bounds__(512) void conv3x3_kernel(
    const float* __restrict__ frm, const float* __restrict__ oth,
    const float* __restrict__ cw, const float* __restrict__ cb,
    float* __restrict__ Fm)
{
    const int w  = threadIdx.x;                      // 0..127
    const int c  = blockIdx.y * 4 + threadIdx.y;     // 0..255
    const int h0 = blockIdx.x * 4;
    const int b  = blockIdx.z;

    float acc0 = 0.f, acc1 = 0.f, acc2 = 0.f, acc3 = 0.f;
    const float* wbase = cw + (size_t)c * (512 * 9);

    #pragma unroll 2
    for (int ci = 0; ci < 512; ci++) {
        const float* xp = ((ci < 256) ? frm : oth)
                        + (((size_t)b * 256 + (ci & 255)) << 14);
        float xv[6][3];
        #pragma unroll
        for (int r = 0; r < 6; r++) {
            const int hh = h0 - 1 + r;
            const bool rv = (hh >= 0) && (hh < HH);
            const float* bp = xp + hh * WW;
            xv[r][0] = (rv && w > 0)      ? bp[w - 1] : 0.f;
            xv[r][1] = rv                 ? bp[w]     : 0.f;
            xv[r][2] = (rv && w < WW - 1) ? bp[w + 1] : 0.f;
        }
        const float* wp = wbase + ci * 9;
        float wv[9];
        #pragma unroll
        for (int j = 0; j < 9; j++) wv[j] = wp[j];

        #pragma unroll
        for (int kh = 0; kh < 3; kh++) {
            #pragma unroll
            for (int kw = 0; kw < 3; kw++) {
                const float g = wv[kh * 3 + kw];
                acc0 = fmaf(g, xv[0 + kh][kw], acc0);
                acc1 = fmaf(g, xv[1 + kh][kw], acc1);
                acc2 = fmaf(g, xv[2 + kh][kw], acc2);
                acc3 = fmaf(g, xv[3 + kh][kw], acc3);
            }
        }
    }

    const float bias = cb[c];
    float o0 = acc0 + bias; o0 = (o0 >= 0.f) ? o0 : 0.01f * o0;
    float o1 = acc1 + bias; o1 = (o1 >= 0.f) ? o1 : 0.01f * o1;
    float o2 = acc2 + bias; o2 = (o2 >= 0.f) ? o2 : 0.01f * o2;
    float o3 = acc3 + bias; o3 = (o3 >= 0.f) ? o3 : 0.01f * o3;

    const size_t base = (((size_t)b * 256 + c) << 14) + ((size_t)h0 << 7) + w;
    Fm[base]           = o0;
    Fm[base + 128]     = o1;
    Fm[base + 256]     = o2;
    Fm[base + 384]     = o3;
}

// ---------------------------------------------------------------------------
// K2a: mode1 reduce — per (b,c) sum+max over contiguous 16384 elems.
// ---------------------------------------------------------------------------
__global__ void reduce_mode1(const float* __restrict__ Fm,
                             float* __restrict__ sum1, float* __restrict__ max1)
{
    const int c = blockIdx.x, b = blockIdx.y;
    const float4* p = (const float4*)(Fm + (((size_t)b * 256 + c) << 14));
    float s = 0.f, m = -INFINITY;
    for (int i = threadIdx.x; i < 4096; i += 256) {
        float4 v = p[i];
        s += v.x + v.y + v.z + v.w;
        m = fmaxf(m, fmaxf(fmaxf(v.x, v.y), fmaxf(v.z, v.w)));
    }
    #pragma unroll
    for (int off = 32; off >= 1; off >>= 1) {
        s += __shfl_xor(s, off);
        m = fmaxf(m, __shfl_xor(m, off));
    }
    __shared__ float ls[4], lm[4];
    const int wave = threadIdx.x >> 6, lane = threadIdx.x & 63;
    if (lane == 0) { ls[wave] = s; lm[wave] = m; }
    __syncthreads();
    if (threadIdx.x == 0) {
        s = ls[0] + ls[1] + ls[2] + ls[3];
        m = fmaxf(fmaxf(lm[0], lm[1]), fmaxf(lm[2], lm[3]));
        sum1[b * 256 + c] = s;
        max1[b * 256 + c] = m;
    }
}

// ---------------------------------------------------------------------------
// K2b: mode2 partials — per (b, c-chunk of 4, w): sum+max over (4c x 128h).
// block 256 = (w:128, par:2). grid(64, 8).
// ---------------------------------------------------------------------------
__global__ void reduce_mode2(const float* __restrict__ Fm,
                             float* __restrict__ p2s, float* __restrict__ p2m)
{
    const int chunk = blockIdx.x, b = blockIdx.y;
    const int w = threadIdx.x & 127, par = threadIdx.x >> 7;
    const float* base = Fm + (((size_t)b * 256 + chunk * 4) << 14);
    float s = 0.f, m = -INFINITY;
    for (int idx = par; idx < 512; idx += 2) {        // idx = c_i*128 + h
        const float v = base[(size_t)idx * 128 + w];
        s += v; m = fmaxf(m, v);
    }
    __shared__ float ls[256], lm[256];
    ls[threadIdx.x] = s; lm[threadIdx.x] = m;
    __syncthreads();
    if (par == 0) {
        s = ls[w] + ls[w + 128];
        m = fmaxf(lm[w], lm[w + 128]);
        p2s[((size_t)b * 64 + chunk) * 128 + w] = s;
        p2m[((size_t)b * 64 + chunk) * 128 + w] = m;
    }
}

// ---------------------------------------------------------------------------
// K2c: mode3 reduce — per (b,h): sum+max over (256c x 128w). grid(128, 8).
// ---------------------------------------------------------------------------
__global__ void reduce_mode3(const float* __restrict__ Fm,
                             float* __restrict__ sum3, float* __restrict__ max3)
{
    const int h = blockIdx.x, b = blockIdx.y;
    float s = 0.f, m = -INFINITY;
    for (int idx = threadIdx.x; idx < 256 * 128; idx += 256) {
        const int ci = idx >> 7, w = idx & 127;
        const float v = Fm[(((size_t)b * 256 + ci) << 14) + (h << 7) + w];
        s += v; m = fmaxf(m, v);
    }
    #pragma unroll
    for (int off = 32; off >= 1; off >>= 1) {
        s += __shfl_xor(s, off);
        m = fmaxf(m, __shfl_xor(m, off));
    }
    __shared__ float ls[4], lm[4];
    const int wave = threadIdx.x >> 6, lane = threadIdx.x & 63;
    if (lane == 0) { ls[wave] = s; lm[wave] = m; }
    __syncthreads();
    if (threadIdx.x == 0) {
        s = ls[0] + ls[1] + ls[2] + ls[3];
        m = fmaxf(fmaxf(lm[0], lm[1]), fmaxf(lm[2], lm[3]));
        sum3[b * 128 + h] = s;
        max3[b * 128 + h] = m;
    }
}

// ---------------------------------------------------------------------------
// K3: tiny per-batch kernel. Computes mode coefficients, U1/U2/U3 (softmax
// over K=4), V1 = recon_w @ U1, spectral attention -> spec[b,c].
// grid(8), block 256.
// ---------------------------------------------------------------------------
__device__ inline float blockSum256(float v, float* red)
{
    #pragma unroll
    for (int off = 32; off >= 1; off >>= 1) v += __shfl_xor(v, off);
    const int wave = threadIdx.x >> 6, lane = threadIdx.x & 63;
    __syncthreads();                 // protect red[] from previous use
    if (lane == 0) red[wave] = v;
    __syncthreads();
    return red[0] + red[1] + red[2] + red[3];
}

__device__ inline void softmax4(const float* A, const float* M, const float* Bc,
                                float avg, float mx, float* u)
{
    float l0 = fmaf(A[0], avg, fmaf(M[0], mx, Bc[0]));
    float l1 = fmaf(A[1], avg, fmaf(M[1], mx, Bc[1]));
    float l2 = fmaf(A[2], avg, fmaf(M[2], mx, Bc[2]));
    float l3 = fmaf(A[3], avg, fmaf(M[3], mx, Bc[3]));
    const float mm = fmaxf(fmaxf(l0, l1), fmaxf(l2, l3));
    const float e0 = expf(l0 - mm), e1 = expf(l1 - mm);
    const float e2 = expf(l2 - mm), e3 = expf(l3 - mm);
    const float inv = 1.f / (e0 + e1 + e2 + e3);
    u[0] = e0 * inv; u[1] = e1 * inv; u[2] = e2 * inv; u[3] = e3 * inv;
}

__global__ void make_u_kernel(
    const float* __restrict__ sum1, const float* __restrict__ max1,
    const float* __restrict__ p2s,  const float* __restrict__ p2m,
    const float* __restrict__ sum3, const float* __restrict__ max3,
    const float* __restrict__ a1w, const float* __restrict__ a1b,
    const float* __restrict__ a2w, const float* __restrict__ a2b,
    const float* __restrict__ a3w, const float* __restrict__ a3b,
    const float* __restrict__ ugw, const float* __restrict__ ugb,
    const float* __restrict__ rw,
    const float* __restrict__ spaw, const float* __restrict__ spab,
    const float* __restrict__ spmw, const float* __restrict__ spmb,
    float* __restrict__ U2g, float* __restrict__ U3g,
    float* __restrict__ V1g, float* __restrict__ specg)
{
    const int b = blockIdx.x, tid = threadIdx.x;

    __shared__ float red[4];
    __shared__ float coefA[3][4], coefM[3][4], coefB[3][4];
    __shared__ float U1s[256][4], U2s[128][4], U3s[128][4];
    __shared__ float gavg[256], gmax[256];

    // ---- coefficients: A_k = ug_w[k,:]·aw[:,0], M_k = ug_w[k,:]·aw[:,1],
    //                    B_k = ug_w[k,:]·ab + ug_b[k]  (per mode) ----
    const float* aws[3]  = { a1w, a2w, a3w };
    const float* abs_[3] = { a1b, a2b, a3b };
    for (int m = 0; m < 3; m++) {
        for (int k = 0; k < 4; k++) {
            const float u = ugw[k * 256 + tid];
            float va = u * aws[m][tid * 2 + 0];
            float vm = u * aws[m][tid * 2 + 1];
            float vb = u * abs_[m][tid];
            va = blockSum256(va, red);
            vm = blockSum256(vm, red);
            vb = blockSum256(vb, red);
            if (tid == 0) {
                coefA[m][k] = va; coefM[m][k] = vm; coefB[m][k] = vb + ugb[k];
            }
        }
    }
    __syncthreads();

    // ---- U1 (mode1: per-c), all 256 threads ----
    {
        const float avg = sum1[b * 256 + tid] * (1.f / 16384.f);
        const float mx  = max1[b * 256 + tid];
        float u[4];
        softmax4(coefA[0], coefM[0], coefB[0], avg, mx, u);
        U1s[tid][0] = u[0]; U1s[tid][1] = u[1]; U1s[tid][2] = u[2]; U1s[tid][3] = u[3];
    }
    // ---- U2 (per-w) and U3 (per-h) ----
    if (tid < 128) {
        const int w = tid;
        float s = 0.f, mx = -INFINITY;
        for (int ch = 0; ch < 64; ch++) {
            s += p2s[((size_t)b * 64 + ch) * 128 + w];
            mx = fmaxf(mx, p2m[((size_t)b * 64 + ch) * 128 + w]);
        }
        const float avg = s * (1.f / 32768.f);
        float u[4];
        softmax4(coefA[1], coefM[1], coefB[1], avg, mx, u);
        float* g = U2g + ((size_t)b * 128 + w) * 4;
        for (int k = 0; k < 4; k++) { U2s[w][k] = u[k]; g[k] = u[k]; }
    } else {
        const int h = tid - 128;
        const float avg = sum3[b * 128 + h] * (1.f / 32768.f);
        const float mx  = max3[b * 128 + h];
        float u[4];
        softmax4(coefA[2], coefM[2], coefB[2], avg, mx, u);
        float* g = U3g + ((size_t)b * 128 + h) * 4;
        for (int k = 0; k < 4; k++) { U3s[h][k] = u[k]; g[k] = u[k]; }
    }
    __syncthreads();

    // ---- V1[b,o,k] = sum_c recon_w[o,c] * U1[b,c,k] ----
    {
        float v0 = 0.f, v1 = 0.f, v2 = 0.f, v3 = 0.f;
        const float* rrow = rw + (size_t)tid * 256;
        for (int c2 = 0; c2 < 256; c2++) {
            const float r = rrow[c2];
            v0 = fmaf(r, U1s[c2][0], v0);
            v1 = fmaf(r, U1s[c2][1], v1);
            v2 = fmaf(r, U1s[c2][2], v2);
            v3 = fmaf(r, U1s[c2][3], v3);
        }
        float* vp = V1g + ((size_t)b * 256 + tid) * 4;
        vp[0] = v0; vp[1] = v1; vp[2] = v2; vp[3] = v3;
    }

    // ---- F_spe stats: g_avg/g_max over n=256 (U23 = [U2;U3]) ----
    {
        const float a0 = U1s[tid][0], a1 = U1s[tid][1];
        const float a2 = U1s[tid][2], a3 = U1s[tid][3];
        float s = 0.f, m = -INFINITY;
        for (int n = 0; n < 256; n++) {
            const float* u23 = (n < 128) ? U2s[n] : U3s[n - 128];
            const float val = a0 * u23[0] + a1 * u23[1] + a2 * u23[2] + a3 * u23[3];
            s += val; m = fmaxf(m, val);
        }
        gavg[tid] = s * (1.f / 256.f);
        gmax[tid] = m;
    }
    __syncthreads();

    // ---- spec = sigmoid(sigmoid(g_avg@spa_w.T + spa_b + g_max@spm_w.T + spm_b)) ----
    {
        float s = spab[tid] + spmb[tid];
        const float* wa = spaw + (size_t)tid * 256;
        const float* wm = spmw + (size_t)tid * 256;
        for (int c2 = 0; c2 < 256; c2++) {
            s = fmaf(gavg[c2], wa[c2], s);
            s = fmaf(gmax[c2], wm[c2], s);
        }
        float sg = 1.f / (1.f + expf(-s));
        sg = 1.f / (1.f + expf(-sg));
        specg[b * 256 + tid] = sg;
    }
}

// ---------------------------------------------------------------------------
// K4: final fused output + CP reconstruction.
// block 256 = (w:128, c-sub:2). grid(H, C/2, B).
// ---------------------------------------------------------------------------
__global__ void final_kernel(
    const float* __restrict__ frm, const float* __restrict__ oth,
    const float* __restrict__ U2g, const float* __restrict__ U3g,
    const float* __restrict__ V1g, const float* __restrict__ specg,
    const float* __restrict__ rb,  const float* __restrict__ spw,
    const float* __restrict__ spb, const float* __restrict__ alphap,
    float* __restrict__ out)
{
    const int w  = threadIdx.x & 127;
    const int cc = threadIdx.x >> 7;
    const int h  = blockIdx.x;
    const int c  = blockIdx.y * 2 + cc;
    const int b  = blockIdx.z;

    const float4 u2 = *(const float4*)(U2g + ((size_t)b * 128 + w) * 4);
    const float4 u3 = *(const float4*)(U3g + ((size_t)b * 128 + h) * 4);
    const float4 v1 = *(const float4*)(V1g + ((size_t)b * 256 + c) * 4);

    const float p0 = u2.x * u3.x, p1 = u2.y * u3.y;
    const float p2 = u2.z * u3.z, p3 = u2.w * u3.w;
    const float dot = p0 + p1 + p2 + p3;
    const float att = 1.f / (1.f + expf(-(spw[0] * dot + spb[0])));
    const float cp  = v1.x * p0 + v1.y * p1 + v1.z * p2 + v1.w * p3 + rb[c];

    const float spec  = specg[b * 256 + c];
    const float Watt  = spec * att;
    const float alpha = alphap[0];

    const size_t idx = (((size_t)b * 256 + c) << 14) + ((size_t)h << 7) + w;
    const float f = frm[idx], o = oth[idx];
    out[idx]          = alpha * Watt * f + (1.f - alpha) * (1.f - Watt) * o;
    out[CP_OFF + idx] = cp;
}

// ---------------------------------------------------------------------------
extern "C" void kernel_launch(void* const* d_in, const int* in_sizes, int n_in,
                              void* d_out, int out_size, void* d_ws, size_t ws_size,
                              hipStream_t stream)
{
    const float* frm   = (const float*)d_in[0];
    const float* oth   = (const float*)d_in[1];
    const float* cw    = (const float*)d_in[2];
    const float* cb    = (const float*)d_in[3];
    const float* a1w   = (const float*)d_in[4];
    const float* a1b   = (const float*)d_in[5];
    const float* a2w   = (const float*)d_in[6];
    const float* a2b   = (const float*)d_in[7];
    const float* a3w   = (const float*)d_in[8];
    const float* a3b   = (const float*)d_in[9];
    const float* ugw   = (const float*)d_in[10];
    const float* ugb   = (const float*)d_in[11];
    const float* rw    = (const float*)d_in[12];
    const float* rb    = (const float*)d_in[13];
    const float* spw   = (const float*)d_in[14];
    const float* spb   = (const float*)d_in[15];
    const float* spaw  = (const float*)d_in[16];
    const float* spab  = (const float*)d_in[17];
    const float* spmw  = (const float*)d_in[18];
    const float* spmb  = (const float*)d_in[19];
    const float* alpha = (const float*)d_in[20];

    float* out = (float*)d_out;
    float* Fm  = out + CP_OFF;            // stage Fm in the cp half of d_out
    float* ws  = (float*)d_ws;

    float* sum1 = ws + WS_SUM1;
    float* max1 = ws + WS_MAX1;
    float* p2s  = ws + WS_P2S;
    float* p2m  = ws + WS_P2M;
    float* sum3 = ws + WS_SUM3;
    float* max3 = ws + WS_MAX3;
    float* U2g  = ws + WS_U2;
    float* U3g  = ws + WS_U3;
    float* V1g  = ws + WS_V1;
    float* spec = ws + WS_SPEC;

    // K1: conv + bias + leaky
    conv3x3_kernel<<<dim3(HH / 4, CC / 4, BB), dim3(128, 4), 0, stream>>>(
        frm, oth, cw, cb, Fm);

    // K2: mode reductions
    reduce_mode1<<<dim3(CC, BB), 256, 0, stream>>>(Fm, sum1, max1);
    reduce_mode2<<<dim3(64, BB), 256, 0, stream>>>(Fm, p2s, p2m);
    reduce_mode3<<<dim3(HH, BB), 256, 0, stream>>>(Fm, sum3, max3);

    // K3: U / V1 / spec
    make_u_kernel<<<dim3(BB), 256, 0, stream>>>(
        sum1, max1, p2s, p2m, sum3, max3,
        a1w, a1b, a2w, a2b, a3w, a3b, ugw, ugb,
        rw, spaw, spab, spmw, spmb,
        U2g, U3g, V1g, spec);

    // K4: fused output + cp (overwrites the Fm staging area last)
    final_kernel<<<dim3(HH, CC / 2, BB), 256, 0, stream>>>(
        frm, oth, U2g, U3g, V1g, spec, rb, spw, spb, alpha, out);
}

// Round 2
// 1130.638 us; speedup vs baseline: 11.7318x; 11.7318x over previous
//
#include <hip/hip_runtime.h>
#include <math.h>

// Problem constants
#define BB 8
#define CC 256
#define HH 128
#define WW 128
#define CP_OFF 33554432          // floats; cp half of d_out

// ---- workspace layout (float offsets) ----
#define ZB_OFF   0               // 256 floats of zeros (OOB load target)
#define P1S_OFF  256             // [8][256][128] f32
#define P1M_OFF  262400          // [8][256][128] u32 (ordered-key max)
#define P2S_OFF  524544          // [8][128]
#define P2M_OFF  525568          // [8][128]
#define P3S_OFF  526592          // [8][128]
#define P3M_OFF  527616          // [8][128]
#define U2_OFF   528640          // [8][128][4]
#define U3_OFF   532736          // [8][128][4]
#define V1_OFF   536832          // [8][256][4]
#define SPEC_OFF 545024          // [8][256]
#define WS_ZERO_BYTES (528640 * 4)   // zero zbuf + all reduction partials

typedef __attribute__((ext_vector_type(8))) short bf16x8;
typedef __attribute__((ext_vector_type(4))) float f32x4;

// ---------------- helpers ----------------
static __device__ __forceinline__ unsigned short f2bf(float f) {
    unsigned u = __float_as_uint(f);
    unsigned r = u + 0x7FFFu + ((u >> 16) & 1u);   // RNE
    return (unsigned short)(r >> 16);
}
static __device__ __forceinline__ unsigned fkey(float f) {
    unsigned u = __float_as_uint(f);
    return (u & 0x80000000u) ? ~u : (u | 0x80000000u);
}
static __device__ __forceinline__ float fkeydec(unsigned k) {
    return __uint_as_float((k & 0x80000000u) ? (k & 0x7FFFFFFFu) : ~k);
}
// async 16B global -> LDS (wave-uniform base + lane*16 semantics)
static __device__ __forceinline__ void gl_lds16(const void* g, void* l) {
    typedef const __attribute__((address_space(1))) unsigned int* gas_t;
    typedef __attribute__((address_space(3))) unsigned int* las_t;
    gas_t gp = (gas_t)(uintptr_t)g;
    las_t lp = (las_t)(unsigned int)(uintptr_t)l;
    __builtin_amdgcn_global_load_lds(gp, lp, 16, 0, 0);
}

// ---------------------------------------------------------------------------
// P1: weights fp32 [co 256][ci 512][3][3] -> Wt bf16 [tap 9][co 256][ci 512]
// ---------------------------------------------------------------------------
__global__ __launch_bounds__(256) void wt_kernel(
    const float* __restrict__ cw, unsigned short* __restrict__ Wt)
{
    const int g = blockIdx.x * 256 + threadIdx.x;    // 0..131071 = co*512+ci
    const int co = g >> 9, ci = g & 511;
    const float* s = cw + (size_t)g * 9;
    #pragma unroll
    for (int t = 0; t < 9; t++)
        Wt[((size_t)t * 256 + co) * 512 + ci] = f2bf(s[t]);
}

// ---------------------------------------------------------------------------
// P2: X transpose: frm/oth fp32 [b][c][h][w] -> Xt bf16 [b][h][w][ci 512]
// block 256 = (w 128, half 2); grid (h 128, b 8). Reads coalesced; writes
// 16B chunks at 1KB stride (L2 assembles full lines).
// ---------------------------------------------------------------------------
__global__ __launch_bounds__(256) void xt_kernel(
    const float* __restrict__ frm, const float* __restrict__ oth,
    unsigned short* __restrict__ Xt)
{
    const int w = threadIdx.x & 127, half = threadIdx.x >> 7;
    const int h = blockIdx.x, b = blockIdx.y;
    const float* src = half ? oth : frm;
    const size_t inbase = (((size_t)b * 256) << 14) + ((size_t)h << 7) + w;
    unsigned short* op = Xt + ((((size_t)(b * 128 + h) * 128) + w) << 9) + half * 256;
    #pragma unroll 2
    for (int c8 = 0; c8 < 32; c8++) {
        unsigned short u[8];
        #pragma unroll
        for (int j = 0; j < 8; j++)
            u[j] = f2bf(src[inbase + (((size_t)(c8 * 8 + j)) << 14)]);
        uint4 pk;
        pk.x = (unsigned)u[0] | ((unsigned)u[1] << 16);
        pk.y = (unsigned)u[2] | ((unsigned)u[3] << 16);
        pk.z = (unsigned)u[4] | ((unsigned)u[5] << 16);
        pk.w = (unsigned)u[6] | ((unsigned)u[7] << 16);
        *(uint4*)(op + c8 * 8) = pk;
    }
}

// ---------------------------------------------------------------------------
// K1: MFMA implicit-GEMM conv + bias + leaky + fused mode reductions.
// Tile: 128 co x 128 px (one h-row of one b). grid(h 128, cohalf 2, b 8),
// block 256 (4 waves in 2x2: wm = co half-64, wn = px half-64).
// K-loop: kh(3) x ci-chunk(16 of 32); per chunk stage A=3 taps (global_load_lds)
// + B=1 X row, then 3 kw x 16 MFMA.
// ---------------------------------------------------------------------------
__global__ __launch_bounds__(256) void conv_mfma(
    const unsigned short* __restrict__ Wt,
    const unsigned short* __restrict__ Xt,
    const float* __restrict__ cb,
    const unsigned short* __restrict__ zb,
    float* __restrict__ p1s, unsigned* __restrict__ p1m,
    float* __restrict__ p2s, unsigned* __restrict__ p2m,
    float* __restrict__ p3s, unsigned* __restrict__ p3m)
{
    // A: [kw 3][ku 4][co 128] 16B units; B: [ku 4][wi 136] 16B units
    __shared__ __align__(16) unsigned short lA[1536 * 8];   // 24576 B
    __shared__ __align__(16) unsigned short lB[544 * 8];    //  8704 B

    const int tid = threadIdx.x;
    const int h = blockIdx.x, cohalf = blockIdx.y, b = blockIdx.z;
    const int lane = tid & 63, wid = tid >> 6;
    const int wm = wid & 1, wn = wid >> 1;
    const int l15 = lane & 15, l4 = lane >> 4;

    f32x4 acc[4][4];
    #pragma unroll
    for (int m = 0; m < 4; m++)
        #pragma unroll
        for (int n = 0; n < 4; n++)
            acc[m][n] = (f32x4){0.f, 0.f, 0.f, 0.f};

    #pragma unroll 1
    for (int kh = 0; kh < 3; kh++) {
        const int hr = h + kh - 1;
        const bool hv = (hr >= 0) && (hr < HH);
        const size_t xrow = ((size_t)(b * 128 + hr)) << 16;   // *128*512

        #pragma unroll 1
        for (int ci0 = 0; ci0 < 512; ci0 += 32) {
            __syncthreads();
            // stage A: 3 taps of this kh, [kw][ku][co], 1536 units
            #pragma unroll
            for (int it = 0; it < 6; it++) {
                const int slot = it * 256 + tid;
                const int kw = slot >> 9;
                const int unit = slot & 511;
                const int ku = unit >> 7, co = unit & 127;
                const unsigned short* g = Wt +
                    ((size_t)((kh * 3 + kw) * 256 + cohalf * 128 + co) * 512 + ci0 + ku * 8);
                gl_lds16(g, &lA[slot * 8]);
            }
            // stage B: row hr, [ku 4][wi 136] (wi-1 = global w; OOB -> zeros)
            #pragma unroll
            for (int it = 0; it < 3; it++) {
                const int slot = it * 256 + tid;
                if (slot < 544) {
                    const int ku = slot / 136;
                    const int wi = slot - ku * 136;
                    const int wg = wi - 1;
                    const bool v = hv && (wg >= 0) && (wg < WW);
                    const unsigned short* g = v
                        ? Xt + (xrow + (((size_t)wg) << 9) + ci0 + ku * 8)
                        : zb;
                    gl_lds16(g, &lB[slot * 8]);
                }
            }
            __syncthreads();
            // compute: 3 kw taps x (4x4 MFMA)
            #pragma unroll
            for (int kw = 0; kw < 3; kw++) {
                bf16x8 af[4], bfr[4];
                #pragma unroll
                for (int m = 0; m < 4; m++) {
                    const int unit = kw * 512 + l4 * 128 + wm * 64 + m * 16 + l15;
                    af[m] = *(const bf16x8*)&lA[unit * 8];
                }
                #pragma unroll
                for (int n = 0; n < 4; n++) {
                    const int unit = l4 * 136 + wn * 64 + n * 16 + l15 + kw;
                    bfr[n] = *(const bf16x8*)&lB[unit * 8];
                }
                #pragma unroll
                for (int m = 0; m < 4; m++)
                    #pragma unroll
                    for (int n = 0; n < 4; n++)
                        acc[m][n] = __builtin_amdgcn_mfma_f32_16x16x32_bf16(
                            af[m], bfr[n], acc[m][n], 0, 0, 0);
            }
        }
    }

    // ---- epilogue: bias + LeakyReLU, then fused mode reductions ----
    // D layout: co = cob + m*16 + l4*4 + r ; px(w) = wn*64 + n*16 + l15
    const int cob = cohalf * 128 + wm * 64;
    float t1s[4][4], t1m[4][4], s2[4], x2[4];
    #pragma unroll
    for (int n = 0; n < 4; n++) { s2[n] = 0.f; x2[n] = -INFINITY; }

    #pragma unroll
    for (int m = 0; m < 4; m++) {
        const float4 bb4 = *(const float4*)&cb[cob + m * 16 + l4 * 4];
        float bbv[4] = { bb4.x, bb4.y, bb4.z, bb4.w };
        #pragma unroll
        for (int r = 0; r < 4; r++) { t1s[m][r] = 0.f; t1m[m][r] = -INFINITY; }
        #pragma unroll
        for (int n = 0; n < 4; n++) {
            #pragma unroll
            for (int r = 0; r < 4; r++) {
                float v = acc[m][n][r] + bbv[r];
                v = (v >= 0.f) ? v : 0.01f * v;
                t1s[m][r] += v;
                t1m[m][r] = fmaxf(t1m[m][r], v);
                s2[n] += v;
                x2[n] = fmaxf(x2[n], v);
            }
        }
    }
    // mode1 (per b,co,h): reduce over w = lane&15 groups
    #pragma unroll
    for (int m = 0; m < 4; m++)
        #pragma unroll
        for (int r = 0; r < 4; r++) {
            float s = t1s[m][r], x = t1m[m][r];
            #pragma unroll
            for (int off = 1; off <= 8; off <<= 1) {
                s += __shfl_xor(s, off);
                x = fmaxf(x, __shfl_xor(x, off));
            }
            t1s[m][r] = s; t1m[m][r] = x;
        }
    if (l15 == 0) {
        #pragma unroll
        for (int m = 0; m < 4; m++)
            #pragma unroll
            for (int r = 0; r < 4; r++) {
                const int co = cob + m * 16 + l4 * 4 + r;
                const int idx = (b * 256 + co) * 128 + h;
                atomicAdd(&p1s[idx], t1s[m][r]);
                atomicMax(&p1m[idx], fkey(t1m[m][r]));
            }
    }
    // mode2 (per b,w): reduce over quads (co), then atomics; accumulate mode3
    float s3 = 0.f, x3 = -INFINITY;
    #pragma unroll
    for (int n = 0; n < 4; n++) {
        float s = s2[n], x = x2[n];
        s += __shfl_xor(s, 16); s += __shfl_xor(s, 32);
        x = fmaxf(x, __shfl_xor(x, 16)); x = fmaxf(x, __shfl_xor(x, 32));
        if (l4 == n) {
            const int w = wn * 64 + n * 16 + l15;
            atomicAdd(&p2s[b * 128 + w], s);
            atomicMax(&p2m[b * 128 + w], fkey(x));
        }
        s3 += s; x3 = fmaxf(x3, x);
    }
    // mode3 (per b,h): reduce over w lanes, one atomic per wave
    #pragma unroll
    for (int off = 1; off <= 8; off <<= 1) {
        s3 += __shfl_xor(s3, off);
        x3 = fmaxf(x3, __shfl_xor(x3, off));
    }
    if (lane == 0) {
        atomicAdd(&p3s[b * 128 + h], s3);
        atomicMax(&p3m[b * 128 + h], fkey(x3));
    }
}

// ---------------------------------------------------------------------------
// K3: tiny per-batch kernel: coefficients, U1/U2/U3, V1, spec. grid(8) x 256.
// ---------------------------------------------------------------------------
__device__ inline float blockSum256(float v, float* red)
{
    #pragma unroll
    for (int off = 32; off >= 1; off >>= 1) v += __shfl_xor(v, off);
    const int wave = threadIdx.x >> 6, lane = threadIdx.x & 63;
    __syncthreads();
    if (lane == 0) red[wave] = v;
    __syncthreads();
    return red[0] + red[1] + red[2] + red[3];
}

__device__ inline void softmax4(const float* A, const float* M, const float* Bc,
                                float avg, float mx, float* u)
{
    float l0 = fmaf(A[0], avg, fmaf(M[0], mx, Bc[0]));
    float l1 = fmaf(A[1], avg, fmaf(M[1], mx, Bc[1]));
    float l2 = fmaf(A[2], avg, fmaf(M[2], mx, Bc[2]));
    float l3 = fmaf(A[3], avg, fmaf(M[3], mx, Bc[3]));
    const float mm = fmaxf(fmaxf(l0, l1), fmaxf(l2, l3));
    const float e0 = expf(l0 - mm), e1 = expf(l1 - mm);
    const float e2 = expf(l2 - mm), e3 = expf(l3 - mm);
    const float inv = 1.f / (e0 + e1 + e2 + e3);
    u[0] = e0 * inv; u[1] = e1 * inv; u[2] = e2 * inv; u[3] = e3 * inv;
}

__global__ void make_u_kernel(
    const float* __restrict__ p1s, const unsigned* __restrict__ p1m,
    const float* __restrict__ p2s, const unsigned* __restrict__ p2m,
    const float* __restrict__ p3s, const unsigned* __restrict__ p3m,
    const float* __restrict__ a1w, const float* __restrict__ a1b,
    const float* __restrict__ a2w, const float* __restrict__ a2b,
    const float* __restrict__ a3w, const float* __restrict__ a3b,
    const float* __restrict__ ugw, const float* __restrict__ ugb,
    const float* __restrict__ rw,
    const float* __restrict__ spaw, const float* __restrict__ spab,
    const float* __restrict__ spmw, const float* __restrict__ spmb,
    float* __restrict__ U2g, float* __restrict__ U3g,
    float* __restrict__ V1g, float* __restrict__ specg)
{
    const int b = blockIdx.x, tid = threadIdx.x;

    __shared__ float red[4];
    __shared__ float coefA[3][4], coefM[3][4], coefB[3][4];
    __shared__ float U1s[256][4], U2s[128][4], U3s[128][4];
    __shared__ float gavg[256], gmax[256];

    const float* aws[3]  = { a1w, a2w, a3w };
    const float* abs_[3] = { a1b, a2b, a3b };
    for (int m = 0; m < 3; m++) {
        for (int k = 0; k < 4; k++) {
            const float u = ugw[k * 256 + tid];
            float va = u * aws[m][tid * 2 + 0];
            float vm = u * aws[m][tid * 2 + 1];
            float vb = u * abs_[m][tid];
            va = blockSum256(va, red);
            vm = blockSum256(vm, red);
            vb = blockSum256(vb, red);
            if (tid == 0) {
                coefA[m][k] = va; coefM[m][k] = vm; coefB[m][k] = vb + ugb[k];
            }
        }
    }
    __syncthreads();

    // U1 (per-c): gather over h partials
    {
        const float* ps = p1s + ((size_t)b * 256 + tid) * 128;
        const unsigned* pm = p1m + ((size_t)b * 256 + tid) * 128;
        float s = 0.f, mx = -INFINITY;
        for (int hh = 0; hh < 128; hh++) {
            s += ps[hh];
            mx = fmaxf(mx, fkeydec(pm[hh]));
        }
        float u[4];
        softmax4(coefA[0], coefM[0], coefB[0], s * (1.f / 16384.f), mx, u);
        U1s[tid][0] = u[0]; U1s[tid][1] = u[1]; U1s[tid][2] = u[2]; U1s[tid][3] = u[3];
    }
    // U2 (per-w) / U3 (per-h)
    if (tid < 128) {
        const float avg = p2s[b * 128 + tid] * (1.f / 32768.f);
        const float mx  = fkeydec(p2m[b * 128 + tid]);
        float u[4];
        softmax4(coefA[1], coefM[1], coefB[1], avg, mx, u);
        float* g = U2g + ((size_t)b * 128 + tid) * 4;
        for (int k = 0; k < 4; k++) { U2s[tid][k] = u[k]; g[k] = u[k]; }
    } else {
        const int hh = tid - 128;
        const float avg = p3s[b * 128 + hh] * (1.f / 32768.f);
        const float mx  = fkeydec(p3m[b * 128 + hh]);
        float u[4];
        softmax4(coefA[2], coefM[2], coefB[2], avg, mx, u);
        float* g = U3g + ((size_t)b * 128 + hh) * 4;
        for (int k = 0; k < 4; k++) { U3s[hh][k] = u[k]; g[k] = u[k]; }
    }
    __syncthreads();

    // V1[b,o,k] = sum_c recon_w[o,c] * U1[b,c,k]
    {
        float v0 = 0.f, v1 = 0.f, v2 = 0.f, v3 = 0.f;
        const float* rrow = rw + (size_t)tid * 256;
        for (int c2 = 0; c2 < 256; c2++) {
            const float r = rrow[c2];
            v0 = fmaf(r, U1s[c2][0], v0);
            v1 = fmaf(r, U1s[c2][1], v1);
            v2 = fmaf(r, U1s[c2][2], v2);
            v3 = fmaf(r, U1s[c2][3], v3);
        }
        float* vp = V1g + ((size_t)b * 256 + tid) * 4;
        vp[0] = v0; vp[1] = v1; vp[2] = v2; vp[3] = v3;
    }
    // F_spe stats
    {
        const float a0 = U1s[tid][0], a1 = U1s[tid][1];
        const float a2 = U1s[tid][2], a3 = U1s[tid][3];
        float s = 0.f, m = -INFINITY;
        for (int n = 0; n < 256; n++) {
            const float* u23 = (n < 128) ? U2s[n] : U3s[n - 128];
            const float val = a0 * u23[0] + a1 * u23[1] + a2 * u23[2] + a3 * u23[3];
            s += val; m = fmaxf(m, val);
        }
        gavg[tid] = s * (1.f / 256.f);
        gmax[tid] = m;
    }
    __syncthreads();
    // spec
    {
        float s = spab[tid] + spmb[tid];
        const float* wa = spaw + (size_t)tid * 256;
        const float* wmp = spmw + (size_t)tid * 256;
        for (int c2 = 0; c2 < 256; c2++) {
            s = fmaf(gavg[c2], wa[c2], s);
            s = fmaf(gmax[c2], wmp[c2], s);
        }
        float sg = 1.f / (1.f + expf(-s));
        sg = 1.f / (1.f + expf(-sg));
        specg[b * 256 + tid] = sg;
    }
}

// ---------------------------------------------------------------------------
// K4: final fused output + CP recon. block 256 = (w 128, c-sub 2).
// ---------------------------------------------------------------------------
__global__ __launch_bounds__(256) void final_kernel(
    const float* __restrict__ frm, const float* __restrict__ oth,
    const float* __restrict__ U2g, const float* __restrict__ U3g,
    const float* __restrict__ V1g, const float* __restrict__ specg,
    const float* __restrict__ rb,  const float* __restrict__ spw,
    const float* __restrict__ spb, const float* __restrict__ alphap,
    float* __restrict__ out)
{
    const int w  = threadIdx.x & 127;
    const int cc = threadIdx.x >> 7;
    const int h  = blockIdx.x;
    const int c  = blockIdx.y * 2 + cc;
    const int b  = blockIdx.z;

    const float4 u2 = *(const float4*)(U2g + ((size_t)b * 128 + w) * 4);
    const float4 u3 = *(const float4*)(U3g + ((size_t)b * 128 + h) * 4);
    const float4 v1 = *(const float4*)(V1g + ((size_t)b * 256 + c) * 4);

    const float p0 = u2.x * u3.x, p1 = u2.y * u3.y;
    const float p2 = u2.z * u3.z, p3 = u2.w * u3.w;
    const float dot = p0 + p1 + p2 + p3;
    const float att = 1.f / (1.f + expf(-(spw[0] * dot + spb[0])));
    const float cp  = v1.x * p0 + v1.y * p1 + v1.z * p2 + v1.w * p3 + rb[c];

    const float spec  = specg[b * 256 + c];
    const float Watt  = spec * att;
    const float alpha = alphap[0];

    const size_t idx = (((size_t)b * 256 + c) << 14) + ((size_t)h << 7) + w;
    const float f = frm[idx], o = oth[idx];
    out[idx]          = alpha * Watt * f + (1.f - alpha) * (1.f - Watt) * o;
    out[CP_OFF + idx] = cp;
}

// ---------------------------------------------------------------------------
extern "C" void kernel_launch(void* const* d_in, const int* in_sizes, int n_in,
                              void* d_out, int out_size, void* d_ws, size_t ws_size,
                              hipStream_t stream)
{
    const float* frm   = (const float*)d_in[0];
    const float* oth   = (const float*)d_in[1];
    const float* cw    = (const float*)d_in[2];
    const float* cb    = (const float*)d_in[3];
    const float* a1w   = (const float*)d_in[4];
    const float* a1b   = (const float*)d_in[5];
    const float* a2w   = (const float*)d_in[6];
    const float* a2b   = (const float*)d_in[7];
    const float* a3w   = (const float*)d_in[8];
    const float* a3b   = (const float*)d_in[9];
    const float* ugw   = (const float*)d_in[10];
    const float* ugb   = (const float*)d_in[11];
    const float* rw    = (const float*)d_in[12];
    const float* rb    = (const float*)d_in[13];
    const float* spw   = (const float*)d_in[14];
    const float* spb   = (const float*)d_in[15];
    const float* spaw  = (const float*)d_in[16];
    const float* spab  = (const float*)d_in[17];
    const float* spmw  = (const float*)d_in[18];
    const float* spmb  = (const float*)d_in[19];
    const float* alpha = (const float*)d_in[20];

    float* out = (float*)d_out;
    float* ws  = (float*)d_ws;

    unsigned short* Wt = (unsigned short*)out;              // 2.36 MB in main half
    unsigned short* Xt = (unsigned short*)(out + CP_OFF);   // 134 MB in cp half

    float*    zb  = ws + ZB_OFF;
    float*    p1s = ws + P1S_OFF;
    unsigned* p1m = (unsigned*)(ws + P1M_OFF);
    float*    p2s = ws + P2S_OFF;
    unsigned* p2m = (unsigned*)(ws + P2M_OFF);
    float*    p3s = ws + P3S_OFF;
    unsigned* p3m = (unsigned*)(ws + P3M_OFF);
    float*    U2g = ws + U2_OFF;
    float*    U3g = ws + U3_OFF;
    float*    V1g = ws + V1_OFF;
    float*    spc = ws + SPEC_OFF;

    // zero zbuf + reduction partials (max keys: 0 == -inf)
    hipMemsetAsync(d_ws, 0, WS_ZERO_BYTES, stream);

    // prep: bf16 operand layouts (staged in d_out, overwritten by final)
    wt_kernel<<<dim3(512), 256, 0, stream>>>(cw, Wt);
    xt_kernel<<<dim3(HH, BB), 256, 0, stream>>>(frm, oth, Xt);

    // conv + fused reductions
    conv_mfma<<<dim3(HH, 2, BB), 256, 0, stream>>>(
        Wt, Xt, cb, (const unsigned short*)zb,
        p1s, p1m, p2s, p2m, p3s, p3m);

    // U / V1 / spec
    make_u_kernel<<<dim3(BB), 256, 0, stream>>>(
        p1s, p1m, p2s, p2m, p3s, p3m,
        a1w, a1b, a2w, a2b, a3w, a3b, ugw, ugb,
        rw, spaw, spab, spmw, spmb,
        U2g, U3g, V1g, spc);

    // fused output + cp (overwrites Wt/Xt staging areas last)
    final_kernel<<<dim3(HH, CC / 2, BB), 256, 0, stream>>>(
        frm, oth, U2g, U3g, V1g, spc, rb, spw, spb, alpha, out);
}